// Round 9
// baseline (137.809 us; speedup 1.0000x reference)
//
#include <hip/hip_runtime.h>
#include <math.h>

#define TOPK 4
#define WAVE 64
#define ROUNDS 9                 // 9 DMA rounds x 64 lanes x 16 B = 9216 B / tile
#define STAGE (ROUNDS * 256)     // 2304 floats staged per tile (mean 2048 + 5.3 sigma)
#define NBUF 4                   // ring of 4 buffers, prefetch distance 3
#define GRID 1024                // 4 single-wave blocks/CU (LDS = 4*9216+16 B)

// Fire-and-forget global->LDS DMA for one tile (wave-uniform dst; HW places
// lane i at dst + 16*i). Source quads clamped in-array; since E%4==0, every
// element e < n_edges lands at its correct LDS slot (clamping only affects
// quads whose entire range is >= n_edges, which the scan bounds never read).
__device__ __forceinline__ void dma_tile(const float* __restrict__ scores,
                                         int base, int clamp_hi, float* dst, int lane)
{
#pragma unroll
    for (int r = 0; r < ROUNDS; ++r) {
        int src = base + (r << 8) + (lane << 2);
        src = src < clamp_hi ? src : clamp_hi;
        __builtin_amdgcn_global_load_lds(
            (const __attribute__((address_space(1))) void*)(scores + src),
            (__attribute__((address_space(3))) void*)(dst + (r << 8)),
            16, 0, 0);
    }
}

// key = mono(score)<<32 | ~edge_idx : u64 compare = (score desc, index asc);
// keys unique so strict '>' reproduces the reference tie-break. 0 never inserts.
__device__ __forceinline__ unsigned long long mkkey(float s, int e)
{
    unsigned u = __float_as_uint(s);
    u ^= 0x80000000u | (unsigned)((int)u >> 31);   // order-preserving map
    return ((unsigned long long)u << 32) | (unsigned)(~e);
}

__global__ __launch_bounds__(WAVE) void segment_top4_kernel(
    const int* __restrict__ row_ptr,
    const float* __restrict__ scores,
    float* __restrict__ vals_out,   // [N,4] float32
    float* __restrict__ idx_out,    // [N,4] indices as float32
    int n_nodes, int n_edges, int n_tiles)
{
    __shared__ float lds[NBUF * STAGE + 4];   // buffers contiguous; +4 tail pad
                                              // (quad overread spills into next
                                              // buffer / pad: read-only garbage,
                                              // masked by the bounds test)
    int b = blockIdx.x;
    if (b >= n_tiles) return;
    int lane = threadIdx.x;
    int G = gridDim.x;
    int clamp_hi = n_edges - 4;

    // ---- prologue: issue DMA for tiles b, b+G, b+2G into buffers 0,1,2 ----
    int base0 = 0, sb0 = 0, se0 = 0;
    int base1 = 0, sb1 = 0, se1 = 0;
    int base2 = 0, sb2 = 0, se2 = 0;
    {
        int node = (b << 6) + lane;
        if (node < n_nodes) { sb0 = row_ptr[node]; se0 = row_ptr[node + 1]; }
        base0 = row_ptr[b << 6] & ~15;
        dma_tile(scores, base0, clamp_hi, lds, lane);
    }
    if (b + G < n_tiles) {
        int t1 = b + G, node = (t1 << 6) + lane;
        if (node < n_nodes) { sb1 = row_ptr[node]; se1 = row_ptr[node + 1]; }
        base1 = row_ptr[t1 << 6] & ~15;
        dma_tile(scores, base1, clamp_hi, lds + STAGE, lane);
    }
    if (b + 2 * G < n_tiles) {
        int t2 = b + 2 * G, node = (t2 << 6) + lane;
        if (node < n_nodes) { sb2 = row_ptr[node]; se2 = row_ptr[node + 1]; }
        base2 = row_ptr[t2 << 6] & ~15;
        dma_tile(scores, base2, clamp_hi, lds + 2 * STAGE, lane);
    }

    int i = 0;
    for (int t = b; t < n_tiles; t += G, ++i) {
        // ---- prefetch tile t+3G into the buffer freed by tile t-G ----
        int tp = t + 3 * G;
        bool pf = tp < n_tiles;                       // block-uniform
        int base3 = 0, sb3 = 0, se3 = 0;
        if (pf) {
            int node = (tp << 6) + lane;
            if (node < n_nodes) { sb3 = row_ptr[node]; se3 = row_ptr[node + 1]; }
            base3 = row_ptr[tp << 6] & ~15;
            asm volatile("" ::: "memory");
            dma_tile(scores, base3, clamp_hi, lds + ((i + 3) & 3) * STAGE, lane);
            // vmcnt retires in issue order. Ops issued after tile t's last DMA
            // (at iter i-3 / prologue): steady 39, i=0: 33, i=1: 35, i=2: 37.
            // Constant 33 is safe for all -> tile t resident, ~3 tiles still
            // in flight through this scan. Never vmcnt(0) in steady state.
            asm volatile("s_waitcnt vmcnt(33)" ::: "memory");
        } else {
            asm volatile("s_waitcnt vmcnt(0)" ::: "memory");   // tail drain
        }

        // ---- scan tile t from its buffer (aligned b128 LDS reads) ----
        const float* buf = lds + (i & 3) * STAGE;
        int lo  = sb0 & ~3;                           // >= base0 (16-aligned)
        int lim = min(se0, base0 + STAGE);
        unsigned long long k0 = 0, k1 = 0, k2 = 0, k3 = 0;
        auto ins = [&](unsigned long long k) {
            bool g0 = k > k0, g1 = k > k1, g2 = k > k2, g3 = k > k3;
            k3 = g3 ? (g2 ? k2 : k) : k3;
            k2 = g2 ? (g1 ? k1 : k) : k2;
            k1 = g1 ? (g0 ? k0 : k) : k1;
            k0 = g0 ? k : k0;
        };
        for (int e = lo; e < lim; e += 4) {
            float4 q = *(const float4*)(buf + (e - base0));
            ins(((e     >= sb0) & (e     < lim)) ? mkkey(q.x, e)     : 0ULL);
            ins(((e + 1 >= sb0) & (e + 1 < lim)) ? mkkey(q.y, e + 1) : 0ULL);
            ins(((e + 2 >= sb0) & (e + 2 < lim)) ? mkkey(q.z, e + 2) : 0ULL);
            ins(((e + 3 >= sb0) & (e + 3 < lim)) ? mkkey(q.w, e + 3) : 0ULL);
        }
        // Overflow fallback (segment past staged window, ~never): issues vmem
        // loads that would corrupt the vmcnt accounting -> self-drain after.
        int ofb = max(sb0, base0 + STAGE);
        if (ofb < se0) {
            for (int e = ofb; e < se0; ++e) ins(mkkey(scores[e], e));
            asm volatile("s_waitcnt vmcnt(0)" ::: "memory");
        }

        // ---- decode + store ----
        int node = (t << 6) + lane;
        if (node < n_nodes) {
            auto dec = [](unsigned long long k, float& v, float& fi) {
                if (k == 0) { v = -INFINITY; fi = -1.0f; return; }
                unsigned hi = (unsigned)(k >> 32);
                unsigned lo32 = (unsigned)k;
                unsigned su = (hi & 0x80000000u) ? (hi ^ 0x80000000u) : ~hi;
                v = __uint_as_float(su);
                fi = (float)(int)(~lo32);
            };
            float4 vo, io;
            dec(k0, vo.x, io.x); dec(k1, vo.y, io.y);
            dec(k2, vo.z, io.z); dec(k3, vo.w, io.w);
            *(float4*)(vals_out + (size_t)node * 4) = vo;
            *(float4*)(idx_out + (size_t)node * 4) = io;
        }

        // ---- rotate ring state ----
        base0 = base1; sb0 = sb1; se0 = se1;
        base1 = base2; sb1 = sb2; se1 = se2;
        base2 = base3; sb2 = sb3; se2 = se3;
    }
}

extern "C" void kernel_launch(void* const* d_in, const int* in_sizes, int n_in,
                              void* d_out, int out_size, void* d_ws, size_t ws_size,
                              hipStream_t stream)
{
    const int*   row_ptr = (const int*)d_in[0];
    const float* scores  = (const float*)d_in[1];
    int n_nodes = in_sizes[0] - 1;
    int n_edges = in_sizes[1];
    int n_tiles = (n_nodes + 63) >> 6;

    float* out      = (float*)d_out;
    float* vals_out = out;                           // first N*4 floats
    float* idx_out  = out + (size_t)n_nodes * TOPK;  // next N*4 floats (idx as f32)

    int grid = n_tiles < GRID ? n_tiles : GRID;
    segment_top4_kernel<<<grid, WAVE, 0, stream>>>(
        row_ptr, scores, vals_out, idx_out, n_nodes, n_edges, n_tiles);
}